// Round 3
// baseline (1044.614 us; speedup 1.0000x reference)
//
#include <hip/hip_runtime.h>
#include <hip/hip_bf16.h>
#include <stdint.h>

#define NA 500000
#define NB 500000
#define EE 1000000
#define SCAN_BLOCKS 489   // ceil(500000/1024)

__device__ __forceinline__ uint32_t f2bf(float f) {
    uint32_t b = __builtin_bit_cast(uint32_t, f);
    return (b + 0x7FFFu + ((b >> 16) & 1u)) >> 16;  // RNE
}

// ---- layer-1 scalar aggregation + CSR histogram, all 3 edge types fused ----
__global__ __launch_bounds__(256) void edge_agg_fused(
    const int* __restrict__ ei_ab, const int* __restrict__ ei_ba,
    const int* __restrict__ ei_aa,
    const float* __restrict__ xa, const float* __restrict__ xb,
    float* __restrict__ agg_ab, float* __restrict__ agg_ba,
    float* __restrict__ agg_aa,
    int* __restrict__ cnt_a, int* __restrict__ cnt_b) {
    int gid = blockIdx.x * 256 + threadIdx.x;
    if (gid < EE) {
        int e = gid;
        int d = ei_ab[EE + e];
        atomicAdd(&agg_ab[d], xa[ei_ab[e]]);
        atomicAdd(&cnt_b[d], 1);
    } else if (gid < 2 * EE) {
        int e = gid - EE;
        int d = ei_ba[EE + e];
        atomicAdd(&agg_ba[d], xb[ei_ba[e]]);
        atomicAdd(&cnt_a[d], 1);
    } else if (gid < 3 * EE) {
        int e = gid - 2 * EE;
        int d = ei_aa[EE + e];
        atomicAdd(&agg_aa[d], xa[ei_aa[e]]);
        atomicAdd(&cnt_a[d], 1);
    }
}

// ---- scan pass 1: per-block (1024 elems) sums ----
__global__ __launch_bounds__(256) void scan1(
    const int* __restrict__ cnt_a, const int* __restrict__ cnt_b,
    int* __restrict__ part_a, int* __restrict__ part_b) {
    const int* cnt = blockIdx.y ? cnt_b : cnt_a;
    int* part = blockIdx.y ? part_b : part_a;
    __shared__ int red[256];
    int t = threadIdx.x;
    int base = blockIdx.x * 1024 + t * 4;
    int s = 0;
#pragma unroll
    for (int k = 0; k < 4; ++k) {
        int i = base + k;
        s += (i < NA) ? cnt[i] : 0;
    }
    red[t] = s;
    __syncthreads();
    for (int off = 128; off > 0; off >>= 1) {
        if (t < off) red[t] += red[t + off];
        __syncthreads();
    }
    if (t == 0) part[blockIdx.x] = red[0];
}

// ---- scan pass 2: exclusive scan of block partials (489 <= 512) in place ----
__global__ __launch_bounds__(512) void scan2(int* __restrict__ part_a,
                                             int* __restrict__ part_b) {
    int* part = blockIdx.y ? part_b : part_a;
    __shared__ int buf[512];
    int t = threadIdx.x;
    buf[t] = (t < SCAN_BLOCKS) ? part[t] : 0;
    __syncthreads();
    for (int off = 1; off < 512; off <<= 1) {
        int v = buf[t];
        if (t >= off) v += buf[t - off];
        __syncthreads();
        buf[t] = v;
        __syncthreads();
    }
    if (t < SCAN_BLOCKS) part[t] = t ? buf[t - 1] : 0;
}

// ---- scan pass 3: per-block exclusive scan + offset -> row_start & cursor ----
__global__ __launch_bounds__(256) void scan3(
    const int* __restrict__ cnt_a, const int* __restrict__ cnt_b,
    const int* __restrict__ part_a, const int* __restrict__ part_b,
    int* __restrict__ row_a, int* __restrict__ row_b,
    int* __restrict__ cur_a, int* __restrict__ cur_b) {
    const int* cnt = blockIdx.y ? cnt_b : cnt_a;
    const int* part = blockIdx.y ? part_b : part_a;
    int* row = blockIdx.y ? row_b : row_a;
    int* cur = blockIdx.y ? cur_b : cur_a;
    __shared__ int red[256];
    int t = threadIdx.x;
    int base = blockIdx.x * 1024 + t * 4;
    int c[4];
    int s = 0;
#pragma unroll
    for (int k = 0; k < 4; ++k) {
        int i = base + k;
        c[k] = (i < NA) ? cnt[i] : 0;
        s += c[k];
    }
    red[t] = s;
    __syncthreads();
    for (int off = 1; off < 256; off <<= 1) {
        int v = red[t];
        if (t >= off) v += red[t - off];
        __syncthreads();
        red[t] = v;
        __syncthreads();
    }
    int e = part[blockIdx.x] + (t ? red[t - 1] : 0);
#pragma unroll
    for (int k = 0; k < 4; ++k) {
        int i = base + k;
        if (i < NA) {
            row[i] = e;
            cur[i] = e;
            if (i == NA - 1) row[NA] = e + c[k];
            e += c[k];
        }
    }
}

// ---- CSR fill: slot = cursor[dst]++; payload = src (| type bit for aa) ----
__global__ __launch_bounds__(256) void csr_fill(
    const int* __restrict__ ei_ab, const int* __restrict__ ei_ba,
    const int* __restrict__ ei_aa,
    int* __restrict__ cur_a, int* __restrict__ cur_b,
    int* __restrict__ csr_a, int* __restrict__ csr_b) {
    int gid = blockIdx.x * 256 + threadIdx.x;
    if (gid < EE) {
        int e = gid;
        int d = ei_ab[EE + e];
        int slot = atomicAdd(&cur_b[d], 1);
        csr_b[slot] = ei_ab[e];
    } else if (gid < 2 * EE) {
        int e = gid - EE;
        int d = ei_ba[EE + e];
        int slot = atomicAdd(&cur_a[d], 1);
        csr_a[slot] = ei_ba[e];                 // type 0 -> tb1
    } else if (gid < 3 * EE) {
        int e = gid - 2 * EE;
        int d = ei_aa[EE + e];
        int slot = atomicAdd(&cur_a[d], 1);
        csr_a[slot] = ei_aa[e] | (1 << 30);     // type 1 -> ta2
    }
}

// ---- gather: 8 lanes per dst node, each lane owns 4 output dims ----
__global__ __launch_bounds__(256) void gather_out(
    const int* __restrict__ row_a, const int* __restrict__ csr_a,
    const int* __restrict__ row_b, const int* __restrict__ csr_b,
    const uint16_t* __restrict__ ta0, const uint16_t* __restrict__ ta2,
    const uint16_t* __restrict__ tb1,
    float* __restrict__ outa, float* __restrict__ outb) {
    int gid = blockIdx.x * 256 + threadIdx.x;   // 8M threads exactly
    int n3 = gid >> 3;
    int l = gid & 7;
    float4 acc = make_float4(0.f, 0.f, 0.f, 0.f);
    if (n3 < NA) {
        int s0 = row_a[n3], s1 = row_a[n3 + 1];
        for (int e = s0; e < s1; ++e) {
            int p = csr_a[e];
            int src = p & 0x3FFFFFFF;
            const uint16_t* tp = (p & (1 << 30)) ? ta2 : tb1;
            uint2 u = *(const uint2*)(tp + (size_t)src * 32 + l * 4);
            acc.x += __builtin_bit_cast(float, u.x << 16);
            acc.y += __builtin_bit_cast(float, u.x & 0xFFFF0000u);
            acc.z += __builtin_bit_cast(float, u.y << 16);
            acc.w += __builtin_bit_cast(float, u.y & 0xFFFF0000u);
        }
        float4* po = (float4*)(outa + (size_t)n3 * 32 + l * 4);
        float4 cur = *po;
        *po = make_float4(cur.x + acc.x, cur.y + acc.y, cur.z + acc.z, cur.w + acc.w);
    } else {
        int n = n3 - NA;
        int s0 = row_b[n], s1 = row_b[n + 1];
        for (int e = s0; e < s1; ++e) {
            int src = csr_b[e];
            uint2 u = *(const uint2*)(ta0 + (size_t)src * 32 + l * 4);
            acc.x += __builtin_bit_cast(float, u.x << 16);
            acc.y += __builtin_bit_cast(float, u.x & 0xFFFF0000u);
            acc.z += __builtin_bit_cast(float, u.y << 16);
            acc.w += __builtin_bit_cast(float, u.y & 0xFFFF0000u);
        }
        float4* po = (float4*)(outb + (size_t)n * 32 + l * 4);
        float4 cur = *po;
        *po = make_float4(cur.x + acc.x, cur.y + acc.y, cur.z + acc.z, cur.w + acc.w);
    }
}

// =================== node A ===================
__global__ __launch_bounds__(256) void node_a_kernel(
    const float* __restrict__ xa,
    const float* __restrict__ s_ba, const float* __restrict__ s_aa,
    const float* __restrict__ Wrel1, const float* __restrict__ Wroot1,
    const float* __restrict__ b1,
    const float* __restrict__ Wrel2, const float* __restrict__ Wroot2,
    const float* __restrict__ b2,
    uint16_t* __restrict__ ta0, uint16_t* __restrict__ ta2,
    float* __restrict__ outa) {
    __shared__ float uS[64], vS[64], wS[64], cS[64], bbS[32];
    __shared__ float W0[2048], W2[2048], WrS[2048];
    __shared__ uint32_t stageU[4352];
    float* stageF = (float*)stageU;
    const int t = threadIdx.x;
    if (t < 64) {
        uS[t] = Wrel1[64 + t];
        vS[t] = Wrel1[128 + t];
        wS[t] = Wroot1[64 + t] + Wroot1[128 + t];
        cS[t] = b1[64 + t] + b1[128 + t];
    }
    if (t >= 64 && t < 96) bbS[t - 64] = b2[32 + (t - 64)] + b2[64 + (t - 64)];
    for (int i = t; i < 2048; i += 256) {
        W0[i]  = Wrel2[i];
        W2[i]  = Wrel2[4096 + i];
        WrS[i] = Wroot2[2048 + i] + Wroot2[4096 + i];
    }
    __syncthreads();

    const int blk = blockIdx.x;
    const int n = blk * 256 + t;
    const bool valid = (n < NA);
    const int validN = (NA - blk * 256) < 256 ? (NA - blk * 256) : 256;
    float sba = 0.f, saa = 0.f, x = 0.f;
    if (valid) { sba = s_ba[n]; saa = s_aa[n]; x = xa[n]; }

    float a0[32], a2[32];
#pragma unroll
    for (int o = 0; o < 32; ++o) { a0[o] = 0.f; a2[o] = 0.f; }
#pragma unroll 2
    for (int j = 0; j < 64; ++j) {
        float hj = fmaxf(fmaf(sba, uS[j], fmaf(saa, vS[j], fmaf(x, wS[j], cS[j]))), 0.f);
        const float4* w0 = (const float4*)(&W0[j * 32]);
        const float4* w2 = (const float4*)(&W2[j * 32]);
#pragma unroll
        for (int q = 0; q < 8; ++q) {
            float4 v0 = w0[q], v2 = w2[q];
            a0[q * 4 + 0] = fmaf(hj, v0.x, a0[q * 4 + 0]);
            a0[q * 4 + 1] = fmaf(hj, v0.y, a0[q * 4 + 1]);
            a0[q * 4 + 2] = fmaf(hj, v0.z, a0[q * 4 + 2]);
            a0[q * 4 + 3] = fmaf(hj, v0.w, a0[q * 4 + 3]);
            a2[q * 4 + 0] = fmaf(hj, v2.x, a2[q * 4 + 0]);
            a2[q * 4 + 1] = fmaf(hj, v2.y, a2[q * 4 + 1]);
            a2[q * 4 + 2] = fmaf(hj, v2.z, a2[q * 4 + 2]);
            a2[q * 4 + 3] = fmaf(hj, v2.w, a2[q * 4 + 3]);
        }
    }

    if (valid) {
#pragma unroll
        for (int k = 0; k < 16; ++k)
            stageU[t * 17 + k] = f2bf(a0[2 * k]) | (f2bf(a0[2 * k + 1]) << 16);
    }
    __syncthreads();
#pragma unroll
    for (int it = 0; it < 4; ++it) {
        int idx4 = t + 256 * it;
        if (idx4 < validN * 4) {
            int node = idx4 >> 2, q = (idx4 & 3) * 4;
            uint4 v = make_uint4(stageU[node * 17 + q], stageU[node * 17 + q + 1],
                                 stageU[node * 17 + q + 2], stageU[node * 17 + q + 3]);
            ((uint4*)ta0)[(size_t)blk * 1024 + idx4] = v;
        }
    }
    __syncthreads();
    if (valid) {
#pragma unroll
        for (int k = 0; k < 16; ++k)
            stageU[t * 17 + k] = f2bf(a2[2 * k]) | (f2bf(a2[2 * k + 1]) << 16);
    }
    __syncthreads();
#pragma unroll
    for (int it = 0; it < 4; ++it) {
        int idx4 = t + 256 * it;
        if (idx4 < validN * 4) {
            int node = idx4 >> 2, q = (idx4 & 3) * 4;
            uint4 v = make_uint4(stageU[node * 17 + q], stageU[node * 17 + q + 1],
                                 stageU[node * 17 + q + 2], stageU[node * 17 + q + 3]);
            ((uint4*)ta2)[(size_t)blk * 1024 + idx4] = v;
        }
    }

    float aR[32];
#pragma unroll
    for (int o = 0; o < 32; ++o) aR[o] = bbS[o];
#pragma unroll 2
    for (int j = 0; j < 64; ++j) {
        float hj = fmaxf(fmaf(sba, uS[j], fmaf(saa, vS[j], fmaf(x, wS[j], cS[j]))), 0.f);
        const float4* wr = (const float4*)(&WrS[j * 32]);
#pragma unroll
        for (int q = 0; q < 8; ++q) {
            float4 wv = wr[q];
            aR[q * 4 + 0] = fmaf(hj, wv.x, aR[q * 4 + 0]);
            aR[q * 4 + 1] = fmaf(hj, wv.y, aR[q * 4 + 1]);
            aR[q * 4 + 2] = fmaf(hj, wv.z, aR[q * 4 + 2]);
            aR[q * 4 + 3] = fmaf(hj, wv.w, aR[q * 4 + 3]);
        }
    }
#pragma unroll 1
    for (int p = 0; p < 2; ++p) {
        __syncthreads();
        int l = t - p * 128;
        if (l >= 0 && l < 128 && valid) {
#pragma unroll
            for (int k = 0; k < 32; ++k) stageF[l * 33 + k] = aR[k];
        }
        __syncthreads();
        int remN = NA - blk * 256 - p * 128;
        int validNp = remN < 0 ? 0 : (remN > 128 ? 128 : remN);
#pragma unroll
        for (int it = 0; it < 4; ++it) {
            int idx4 = t + 256 * it;
            if (idx4 < validNp * 8) {
                int node = idx4 >> 3, q = (idx4 & 7) * 4;
                float4 v = make_float4(stageF[node * 33 + q], stageF[node * 33 + q + 1],
                                       stageF[node * 33 + q + 2], stageF[node * 33 + q + 3]);
                ((float4*)outa)[(size_t)blk * 2048 + p * 1024 + idx4] = v;
            }
        }
    }
}

// =================== node B ===================
__global__ __launch_bounds__(256) void node_b_kernel(
    const float* __restrict__ xb, const float* __restrict__ s_ab,
    const float* __restrict__ Wrel1, const float* __restrict__ Wroot1,
    const float* __restrict__ b1,
    const float* __restrict__ Wrel2, const float* __restrict__ Wroot2,
    const float* __restrict__ b2,
    uint16_t* __restrict__ tb1, float* __restrict__ outb) {
    __shared__ float uS[64], wS[64], cS[64], bbS[32];
    __shared__ float W1[2048], WrS[2048];
    __shared__ uint32_t stageU[4352];
    float* stageF = (float*)stageU;
    const int t = threadIdx.x;
    if (t < 64) {
        uS[t] = Wrel1[t];
        wS[t] = Wroot1[t];
        cS[t] = b1[t];
    }
    if (t >= 64 && t < 96) bbS[t - 64] = b2[t - 64];
    for (int i = t; i < 2048; i += 256) {
        W1[i]  = Wrel2[2048 + i];
        WrS[i] = Wroot2[i];
    }
    __syncthreads();

    const int blk = blockIdx.x;
    const int n = blk * 256 + t;
    const bool valid = (n < NB);
    const int validN = (NB - blk * 256) < 256 ? (NB - blk * 256) : 256;
    float sab = 0.f, x = 0.f;
    if (valid) { sab = s_ab[n]; x = xb[n]; }

    float a1[32], aR[32];
#pragma unroll
    for (int o = 0; o < 32; ++o) { a1[o] = 0.f; aR[o] = bbS[o]; }
#pragma unroll 2
    for (int j = 0; j < 64; ++j) {
        float hj = fmaxf(fmaf(sab, uS[j], fmaf(x, wS[j], cS[j])), 0.f);
        const float4* w1 = (const float4*)(&W1[j * 32]);
        const float4* wr = (const float4*)(&WrS[j * 32]);
#pragma unroll
        for (int q = 0; q < 8; ++q) {
            float4 v1 = w1[q], vr = wr[q];
            a1[q * 4 + 0] = fmaf(hj, v1.x, a1[q * 4 + 0]);
            a1[q * 4 + 1] = fmaf(hj, v1.y, a1[q * 4 + 1]);
            a1[q * 4 + 2] = fmaf(hj, v1.z, a1[q * 4 + 2]);
            a1[q * 4 + 3] = fmaf(hj, v1.w, a1[q * 4 + 3]);
            aR[q * 4 + 0] = fmaf(hj, vr.x, aR[q * 4 + 0]);
            aR[q * 4 + 1] = fmaf(hj, vr.y, aR[q * 4 + 1]);
            aR[q * 4 + 2] = fmaf(hj, vr.z, aR[q * 4 + 2]);
            aR[q * 4 + 3] = fmaf(hj, vr.w, aR[q * 4 + 3]);
        }
    }

    if (valid) {
#pragma unroll
        for (int k = 0; k < 16; ++k)
            stageU[t * 17 + k] = f2bf(a1[2 * k]) | (f2bf(a1[2 * k + 1]) << 16);
    }
    __syncthreads();
#pragma unroll
    for (int it = 0; it < 4; ++it) {
        int idx4 = t + 256 * it;
        if (idx4 < validN * 4) {
            int node = idx4 >> 2, q = (idx4 & 3) * 4;
            uint4 v = make_uint4(stageU[node * 17 + q], stageU[node * 17 + q + 1],
                                 stageU[node * 17 + q + 2], stageU[node * 17 + q + 3]);
            ((uint4*)tb1)[(size_t)blk * 1024 + idx4] = v;
        }
    }

#pragma unroll 1
    for (int p = 0; p < 2; ++p) {
        __syncthreads();
        int l = t - p * 128;
        if (l >= 0 && l < 128 && valid) {
#pragma unroll
            for (int k = 0; k < 32; ++k) stageF[l * 33 + k] = aR[k];
        }
        __syncthreads();
        int remN = NB - blk * 256 - p * 128;
        int validNp = remN < 0 ? 0 : (remN > 128 ? 128 : remN);
#pragma unroll
        for (int it = 0; it < 4; ++it) {
            int idx4 = t + 256 * it;
            if (idx4 < validNp * 8) {
                int node = idx4 >> 3, q = (idx4 & 7) * 4;
                float4 v = make_float4(stageF[node * 33 + q], stageF[node * 33 + q + 1],
                                       stageF[node * 33 + q + 2], stageF[node * 33 + q + 3]);
                ((float4*)outb)[(size_t)blk * 2048 + p * 1024 + idx4] = v;
            }
        }
    }
}

extern "C" void kernel_launch(void* const* d_in, const int* in_sizes, int n_in,
                              void* d_out, int out_size, void* d_ws, size_t ws_size,
                              hipStream_t stream) {
    const float* x_a    = (const float*)d_in[0];
    const float* x_b    = (const float*)d_in[1];
    const int*   ei_ab  = (const int*)d_in[2];
    const int*   ei_ba  = (const int*)d_in[3];
    const int*   ei_aa  = (const int*)d_in[4];
    const float* Wrel1  = (const float*)d_in[5];
    const float* Wroot1 = (const float*)d_in[6];
    const float* b1     = (const float*)d_in[7];
    const float* Wrel2  = (const float*)d_in[8];
    const float* Wroot2 = (const float*)d_in[9];
    const float* b2     = (const float*)d_in[10];

    float* outa = (float*)d_out;                       // [NA,32]
    float* outb = (float*)d_out + (size_t)NA * 32;     // [NB,32]

    char* ws = (char*)d_ws;
    float*    agg_ab = (float*)(ws);                          // NB floats, 2 MB
    float*    agg_ba = (float*)(ws + 2000000);                // NA floats
    float*    agg_aa = (float*)(ws + 4000000);                // NA floats
    uint16_t* ta0    = (uint16_t*)(ws + 6000000);             // NA*32 bf16
    uint16_t* ta2    = (uint16_t*)(ws + 38000000);            // NA*32 bf16
    uint16_t* tb1    = (uint16_t*)(ws + 70000000);            // NB*32 bf16
    int*      cnt_a  = (int*)(ws + 102000000);                // NA (also cursor)
    int*      cnt_b  = (int*)(ws + 104000000);                // NB (also cursor)
    int*      row_a  = (int*)(ws + 106000000);                // NA+1
    int*      row_b  = (int*)(ws + 108000008);                // NB+1
    int*      csr_a  = (int*)(ws + 110000016);                // 2M ints
    int*      csr_b  = (int*)(ws + 118000016);                // 1M ints
    int*      part_a = (int*)(ws + 122000016);                // 489 ints
    int*      part_b = (int*)(ws + 122002048);                // 489 ints
    if (ws_size < 122500000) return;  // need ~122.1 MB scratch

    hipMemsetAsync(ws, 0, 6000000, stream);               // agg arrays
    hipMemsetAsync(ws + 102000000, 0, 4000000, stream);   // cnt_a, cnt_b

    dim3 blk(256);
    int egrid = (3 * EE + 255) / 256;
    edge_agg_fused<<<egrid, blk, 0, stream>>>(ei_ab, ei_ba, ei_aa, x_a, x_b,
                                              agg_ab, agg_ba, agg_aa, cnt_a, cnt_b);

    // CSR build (independent of node kernels)
    scan1<<<dim3(SCAN_BLOCKS, 2), blk, 0, stream>>>(cnt_a, cnt_b, part_a, part_b);
    scan2<<<dim3(1, 2), dim3(512), 0, stream>>>(part_a, part_b);
    scan3<<<dim3(SCAN_BLOCKS, 2), blk, 0, stream>>>(cnt_a, cnt_b, part_a, part_b,
                                                    row_a, row_b, cnt_a, cnt_b);
    csr_fill<<<egrid, blk, 0, stream>>>(ei_ab, ei_ba, ei_aa, cnt_a, cnt_b,
                                        csr_a, csr_b);

    int ngrid = (NA + 255) / 256;
    node_a_kernel<<<ngrid, blk, 0, stream>>>(x_a, agg_ba, agg_aa, Wrel1, Wroot1,
                                             b1, Wrel2, Wroot2, b2, ta0, ta2, outa);
    node_b_kernel<<<ngrid, blk, 0, stream>>>(x_b, agg_ab, Wrel1, Wroot1, b1,
                                             Wrel2, Wroot2, b2, tb1, outb);

    int ggrid = (int)(((size_t)(NA + NB) * 8 + 255) / 256);  // 31250
    gather_out<<<ggrid, blk, 0, stream>>>(row_a, csr_a, row_b, csr_b,
                                          ta0, ta2, tb1, outa, outb);
}

// Round 4
// 705.692 us; speedup vs baseline: 1.4803x; 1.4803x over previous
//
#include <hip/hip_runtime.h>
#include <hip/hip_bf16.h>
#include <stdint.h>

#define NA 500000
#define NB 500000
#define EE 1000000
#define NBUCK 3907          // ceil(500000/128)
#define CAPA 704            // mean 512, sd ~22.6 -> +8.5 sigma
#define CAPB 416            // mean 256, sd ~16  -> +10 sigma
#define OCAP 4096

__device__ __forceinline__ uint32_t f2bf(float f) {
    uint32_t b = __builtin_bit_cast(uint32_t, f);
    return (b + 0x7FFFu + ((b >> 16) & 1u)) >> 16;  // RNE
}

// ---- K1: bucket scatter. entry = src | type<<19 | dstLocal<<20 ----
__global__ __launch_bounds__(256) void bucket_scatter(
    const int* __restrict__ ei_ab, const int* __restrict__ ei_ba,
    const int* __restrict__ ei_aa,
    int* __restrict__ cnt_a, int* __restrict__ cnt_b,
    uint32_t* __restrict__ buck_a, uint32_t* __restrict__ buck_b,
    int* __restrict__ ocnt, uint2* __restrict__ oflow) {
    int gid = blockIdx.x * 256 + threadIdx.x;
    if (gid >= 3 * EE) return;
    int dst, src, type, famA;
    if (gid < EE) {                 // ab -> dst is b-node, src indexes xa/ta0
        dst = ei_ab[EE + gid]; src = ei_ab[gid]; type = 0; famA = 0;
    } else if (gid < 2 * EE) {      // ba -> dst a-node, src indexes xb/tb1
        int e = gid - EE;
        dst = ei_ba[EE + e]; src = ei_ba[e]; type = 0; famA = 1;
    } else {                        // aa -> dst a-node, src indexes xa/ta2
        int e = gid - 2 * EE;
        dst = ei_aa[EE + e]; src = ei_aa[e]; type = 1; famA = 1;
    }
    int bucket = dst >> 7;
    uint32_t entry = (uint32_t)src | ((uint32_t)type << 19) |
                     ((uint32_t)(dst & 127) << 20);
    int cap = famA ? CAPA : CAPB;
    int* cnt = famA ? cnt_a : cnt_b;
    uint32_t* buck = famA ? buck_a : buck_b;
    int slot = atomicAdd(&cnt[bucket], 1);
    if (slot < cap) {
        buck[(size_t)bucket * cap + slot] = entry;
    } else {
        int o = atomicAdd(ocnt, 1);
        if (o < OCAP)
            oflow[o] = make_uint2((uint32_t)dst | ((uint32_t)famA << 30) |
                                  ((uint32_t)type << 29), (uint32_t)src);
    }
}

// ---- K2: per-bucket counting sort in LDS + layer-1 scalar aggregation ----
__global__ __launch_bounds__(256) void sort_agg(
    const int* __restrict__ cnt_a, const int* __restrict__ cnt_b,
    uint32_t* __restrict__ buck_a, uint32_t* __restrict__ buck_b,
    const float* __restrict__ xa, const float* __restrict__ xb,
    float* __restrict__ agg_ba, float* __restrict__ agg_aa,
    float* __restrict__ agg_ab,
    uint16_t* __restrict__ start16_a, uint16_t* __restrict__ start16_b) {
    __shared__ uint32_t raw[CAPA];
    __shared__ uint32_t sorted[CAPA];
    __shared__ int hist[128], cursor[128], startS[128], fillC[128];
    __shared__ float sAgg[256];
    const int bucket = blockIdx.x;
    const int isA = (blockIdx.y == 0);
    const int cap = isA ? CAPA : CAPB;
    uint32_t* buck = (isA ? buck_a : buck_b) + (size_t)bucket * cap;
    int K = isA ? cnt_a[bucket] : cnt_b[bucket];
    K = K < cap ? K : cap;
    const int t = threadIdx.x;
    if (t < 128) hist[t] = 0;
    sAgg[t] = 0.f;
    __syncthreads();
    for (int i = t; i < K; i += 256) {
        uint32_t e = buck[i];
        raw[i] = e;
        atomicAdd(&hist[e >> 20], 1);
    }
    __syncthreads();
    // inclusive scan of hist -> cursor
    if (t < 128) cursor[t] = hist[t];
    __syncthreads();
    for (int off = 1; off < 128; off <<= 1) {
        int v = 0;
        if (t < 128) { v = cursor[t]; if (t >= off) v += cursor[t - off]; }
        __syncthreads();
        if (t < 128) cursor[t] = v;
        __syncthreads();
    }
    if (t < 128) {
        int st = cursor[t] - hist[t];   // exclusive
        startS[t] = st;
        fillC[t] = st;
    }
    __syncthreads();
    // place + aggregate
    for (int i = t; i < K; i += 256) {
        uint32_t e = raw[i];
        int loc = e >> 20;
        int type = (e >> 19) & 1;
        int src = e & 0x7FFFF;
        int pos = atomicAdd(&fillC[loc], 1);
        sorted[pos] = e;
        float xv = isA ? (type ? xa[src] : xb[src]) : xa[src];
        atomicAdd(&sAgg[loc * 2 + type], xv);
    }
    __syncthreads();
    for (int i = t; i < K; i += 256) buck[i] = sorted[i];
    if (t < 128) {
        int n = bucket * 128 + t;
        if (isA) {
            start16_a[bucket * 128 + t] = (uint16_t)startS[t];
            if (n < NA) {
                agg_ba[n] = sAgg[t * 2];
                agg_aa[n] = sAgg[t * 2 + 1];
            }
        } else {
            start16_b[bucket * 128 + t] = (uint16_t)startS[t];
            if (n < NB) agg_ab[n] = sAgg[t * 2];
        }
    }
}

// ---- K2b: overflow agg fixup (normally zero iterations) ----
__global__ __launch_bounds__(256) void oflow_agg(
    const int* __restrict__ ocnt, const uint2* __restrict__ oflow,
    const float* __restrict__ xa, const float* __restrict__ xb,
    float* __restrict__ agg_ba, float* __restrict__ agg_aa,
    float* __restrict__ agg_ab) {
    int n = *ocnt;
    n = n < OCAP ? n : OCAP;
    for (int i = threadIdx.x; i < n; i += 256) {
        uint2 r = oflow[i];
        int dst = r.x & 0x1FFFFFFF;
        int famA = (r.x >> 30) & 1;
        int type = (r.x >> 29) & 1;
        int src = (int)r.y;
        if (famA) {
            if (type) atomicAdd(&agg_aa[dst], xa[src]);
            else      atomicAdd(&agg_ba[dst], xb[src]);
        } else {
            atomicAdd(&agg_ab[dst], xa[src]);
        }
    }
}

// ---- K5: overflow out fixup (after gather; normally zero iterations) ----
__global__ __launch_bounds__(256) void oflow_out(
    const int* __restrict__ ocnt, const uint2* __restrict__ oflow,
    const uint16_t* __restrict__ ta0, const uint16_t* __restrict__ ta2,
    const uint16_t* __restrict__ tb1,
    float* __restrict__ outa, float* __restrict__ outb) {
    int n = *ocnt;
    n = n < OCAP ? n : OCAP;
    for (int i = threadIdx.x; i < n; i += 256) {
        uint2 r = oflow[i];
        int dst = r.x & 0x1FFFFFFF;
        int famA = (r.x >> 30) & 1;
        int type = (r.x >> 29) & 1;
        int src = (int)r.y;
        const uint16_t* tp = famA ? (type ? ta2 : tb1) : ta0;
        float* out = famA ? outa : outb;
        for (int k = 0; k < 32; ++k) {
            float v = __builtin_bit_cast(float,
                          (uint32_t)tp[(size_t)src * 32 + k] << 16);
            atomicAdd(&out[(size_t)dst * 32 + k], v);
        }
    }
}

// ---- K4: gather, 8 lanes per dst node ----
__global__ __launch_bounds__(256) void gather_out(
    const int* __restrict__ cnt_a, const int* __restrict__ cnt_b,
    const uint16_t* __restrict__ start16_a, const uint16_t* __restrict__ start16_b,
    const uint32_t* __restrict__ buck_a, const uint32_t* __restrict__ buck_b,
    const uint16_t* __restrict__ ta0, const uint16_t* __restrict__ ta2,
    const uint16_t* __restrict__ tb1,
    float* __restrict__ outa, float* __restrict__ outb) {
    int gid = blockIdx.x * 256 + threadIdx.x;   // exactly (NA+NB)*8 threads
    int n3 = gid >> 3;
    int l = gid & 7;
    float4 acc = make_float4(0.f, 0.f, 0.f, 0.f);
    if (n3 < NA) {
        int bucket = n3 >> 7, local = n3 & 127;
        int start = start16_a[n3];
        int end;
        if (local == 127) {
            int K = cnt_a[bucket];
            end = K < CAPA ? K : CAPA;
        } else end = start16_a[n3 + 1];
        const uint32_t* bp = buck_a + (size_t)bucket * CAPA;
        for (int i = start; i < end; ++i) {
            uint32_t e = bp[i];
            int src = e & 0x7FFFF;
            const uint16_t* tp = (e & (1u << 19)) ? ta2 : tb1;
            uint2 u = *(const uint2*)(tp + (size_t)src * 32 + l * 4);
            acc.x += __builtin_bit_cast(float, u.x << 16);
            acc.y += __builtin_bit_cast(float, u.x & 0xFFFF0000u);
            acc.z += __builtin_bit_cast(float, u.y << 16);
            acc.w += __builtin_bit_cast(float, u.y & 0xFFFF0000u);
        }
        float4* po = (float4*)(outa + (size_t)n3 * 32 + l * 4);
        float4 cur = *po;
        *po = make_float4(cur.x + acc.x, cur.y + acc.y, cur.z + acc.z, cur.w + acc.w);
    } else {
        int n = n3 - NA;
        int bucket = n >> 7, local = n & 127;
        int start = start16_b[n];
        int end;
        if (local == 127) {
            int K = cnt_b[bucket];
            end = K < CAPB ? K : CAPB;
        } else end = start16_b[n + 1];
        const uint32_t* bp = buck_b + (size_t)bucket * CAPB;
        for (int i = start; i < end; ++i) {
            uint32_t e = bp[i];
            int src = e & 0x7FFFF;
            uint2 u = *(const uint2*)(ta0 + (size_t)src * 32 + l * 4);
            acc.x += __builtin_bit_cast(float, u.x << 16);
            acc.y += __builtin_bit_cast(float, u.x & 0xFFFF0000u);
            acc.z += __builtin_bit_cast(float, u.y << 16);
            acc.w += __builtin_bit_cast(float, u.y & 0xFFFF0000u);
        }
        float4* po = (float4*)(outb + (size_t)n * 32 + l * 4);
        float4 cur = *po;
        *po = make_float4(cur.x + acc.x, cur.y + acc.y, cur.z + acc.z, cur.w + acc.w);
    }
}

// =================== node A (unchanged from R2) ===================
__global__ __launch_bounds__(256) void node_a_kernel(
    const float* __restrict__ xa,
    const float* __restrict__ s_ba, const float* __restrict__ s_aa,
    const float* __restrict__ Wrel1, const float* __restrict__ Wroot1,
    const float* __restrict__ b1,
    const float* __restrict__ Wrel2, const float* __restrict__ Wroot2,
    const float* __restrict__ b2,
    uint16_t* __restrict__ ta0, uint16_t* __restrict__ ta2,
    float* __restrict__ outa) {
    __shared__ float uS[64], vS[64], wS[64], cS[64], bbS[32];
    __shared__ float W0[2048], W2[2048], WrS[2048];
    __shared__ uint32_t stageU[4352];
    float* stageF = (float*)stageU;
    const int t = threadIdx.x;
    if (t < 64) {
        uS[t] = Wrel1[64 + t];
        vS[t] = Wrel1[128 + t];
        wS[t] = Wroot1[64 + t] + Wroot1[128 + t];
        cS[t] = b1[64 + t] + b1[128 + t];
    }
    if (t >= 64 && t < 96) bbS[t - 64] = b2[32 + (t - 64)] + b2[64 + (t - 64)];
    for (int i = t; i < 2048; i += 256) {
        W0[i]  = Wrel2[i];
        W2[i]  = Wrel2[4096 + i];
        WrS[i] = Wroot2[2048 + i] + Wroot2[4096 + i];
    }
    __syncthreads();

    const int blk = blockIdx.x;
    const int n = blk * 256 + t;
    const bool valid = (n < NA);
    const int validN = (NA - blk * 256) < 256 ? (NA - blk * 256) : 256;
    float sba = 0.f, saa = 0.f, x = 0.f;
    if (valid) { sba = s_ba[n]; saa = s_aa[n]; x = xa[n]; }

    float a0[32], a2[32];
#pragma unroll
    for (int o = 0; o < 32; ++o) { a0[o] = 0.f; a2[o] = 0.f; }
#pragma unroll 2
    for (int j = 0; j < 64; ++j) {
        float hj = fmaxf(fmaf(sba, uS[j], fmaf(saa, vS[j], fmaf(x, wS[j], cS[j]))), 0.f);
        const float4* w0 = (const float4*)(&W0[j * 32]);
        const float4* w2 = (const float4*)(&W2[j * 32]);
#pragma unroll
        for (int q = 0; q < 8; ++q) {
            float4 v0 = w0[q], v2 = w2[q];
            a0[q * 4 + 0] = fmaf(hj, v0.x, a0[q * 4 + 0]);
            a0[q * 4 + 1] = fmaf(hj, v0.y, a0[q * 4 + 1]);
            a0[q * 4 + 2] = fmaf(hj, v0.z, a0[q * 4 + 2]);
            a0[q * 4 + 3] = fmaf(hj, v0.w, a0[q * 4 + 3]);
            a2[q * 4 + 0] = fmaf(hj, v2.x, a2[q * 4 + 0]);
            a2[q * 4 + 1] = fmaf(hj, v2.y, a2[q * 4 + 1]);
            a2[q * 4 + 2] = fmaf(hj, v2.z, a2[q * 4 + 2]);
            a2[q * 4 + 3] = fmaf(hj, v2.w, a2[q * 4 + 3]);
        }
    }

    if (valid) {
#pragma unroll
        for (int k = 0; k < 16; ++k)
            stageU[t * 17 + k] = f2bf(a0[2 * k]) | (f2bf(a0[2 * k + 1]) << 16);
    }
    __syncthreads();
#pragma unroll
    for (int it = 0; it < 4; ++it) {
        int idx4 = t + 256 * it;
        if (idx4 < validN * 4) {
            int node = idx4 >> 2, q = (idx4 & 3) * 4;
            uint4 v = make_uint4(stageU[node * 17 + q], stageU[node * 17 + q + 1],
                                 stageU[node * 17 + q + 2], stageU[node * 17 + q + 3]);
            ((uint4*)ta0)[(size_t)blk * 1024 + idx4] = v;
        }
    }
    __syncthreads();
    if (valid) {
#pragma unroll
        for (int k = 0; k < 16; ++k)
            stageU[t * 17 + k] = f2bf(a2[2 * k]) | (f2bf(a2[2 * k + 1]) << 16);
    }
    __syncthreads();
#pragma unroll
    for (int it = 0; it < 4; ++it) {
        int idx4 = t + 256 * it;
        if (idx4 < validN * 4) {
            int node = idx4 >> 2, q = (idx4 & 3) * 4;
            uint4 v = make_uint4(stageU[node * 17 + q], stageU[node * 17 + q + 1],
                                 stageU[node * 17 + q + 2], stageU[node * 17 + q + 3]);
            ((uint4*)ta2)[(size_t)blk * 1024 + idx4] = v;
        }
    }

    float aR[32];
#pragma unroll
    for (int o = 0; o < 32; ++o) aR[o] = bbS[o];
#pragma unroll 2
    for (int j = 0; j < 64; ++j) {
        float hj = fmaxf(fmaf(sba, uS[j], fmaf(saa, vS[j], fmaf(x, wS[j], cS[j]))), 0.f);
        const float4* wr = (const float4*)(&WrS[j * 32]);
#pragma unroll
        for (int q = 0; q < 8; ++q) {
            float4 wv = wr[q];
            aR[q * 4 + 0] = fmaf(hj, wv.x, aR[q * 4 + 0]);
            aR[q * 4 + 1] = fmaf(hj, wv.y, aR[q * 4 + 1]);
            aR[q * 4 + 2] = fmaf(hj, wv.z, aR[q * 4 + 2]);
            aR[q * 4 + 3] = fmaf(hj, wv.w, aR[q * 4 + 3]);
        }
    }
#pragma unroll 1
    for (int p = 0; p < 2; ++p) {
        __syncthreads();
        int l = t - p * 128;
        if (l >= 0 && l < 128 && valid) {
#pragma unroll
            for (int k = 0; k < 32; ++k) stageF[l * 33 + k] = aR[k];
        }
        __syncthreads();
        int remN = NA - blk * 256 - p * 128;
        int validNp = remN < 0 ? 0 : (remN > 128 ? 128 : remN);
#pragma unroll
        for (int it = 0; it < 4; ++it) {
            int idx4 = t + 256 * it;
            if (idx4 < validNp * 8) {
                int node = idx4 >> 3, q = (idx4 & 7) * 4;
                float4 v = make_float4(stageF[node * 33 + q], stageF[node * 33 + q + 1],
                                       stageF[node * 33 + q + 2], stageF[node * 33 + q + 3]);
                ((float4*)outa)[(size_t)blk * 2048 + p * 1024 + idx4] = v;
            }
        }
    }
}

// =================== node B (unchanged from R2) ===================
__global__ __launch_bounds__(256) void node_b_kernel(
    const float* __restrict__ xb, const float* __restrict__ s_ab,
    const float* __restrict__ Wrel1, const float* __restrict__ Wroot1,
    const float* __restrict__ b1,
    const float* __restrict__ Wrel2, const float* __restrict__ Wroot2,
    const float* __restrict__ b2,
    uint16_t* __restrict__ tb1, float* __restrict__ outb) {
    __shared__ float uS[64], wS[64], cS[64], bbS[32];
    __shared__ float W1[2048], WrS[2048];
    __shared__ uint32_t stageU[4352];
    float* stageF = (float*)stageU;
    const int t = threadIdx.x;
    if (t < 64) {
        uS[t] = Wrel1[t];
        wS[t] = Wroot1[t];
        cS[t] = b1[t];
    }
    if (t >= 64 && t < 96) bbS[t - 64] = b2[t - 64];
    for (int i = t; i < 2048; i += 256) {
        W1[i]  = Wrel2[2048 + i];
        WrS[i] = Wroot2[i];
    }
    __syncthreads();

    const int blk = blockIdx.x;
    const int n = blk * 256 + t;
    const bool valid = (n < NB);
    const int validN = (NB - blk * 256) < 256 ? (NB - blk * 256) : 256;
    float sab = 0.f, x = 0.f;
    if (valid) { sab = s_ab[n]; x = xb[n]; }

    float a1[32], aR[32];
#pragma unroll
    for (int o = 0; o < 32; ++o) { a1[o] = 0.f; aR[o] = bbS[o]; }
#pragma unroll 2
    for (int j = 0; j < 64; ++j) {
        float hj = fmaxf(fmaf(sab, uS[j], fmaf(x, wS[j], cS[j])), 0.f);
        const float4* w1 = (const float4*)(&W1[j * 32]);
        const float4* wr = (const float4*)(&WrS[j * 32]);
#pragma unroll
        for (int q = 0; q < 8; ++q) {
            float4 v1 = w1[q], vr = wr[q];
            a1[q * 4 + 0] = fmaf(hj, v1.x, a1[q * 4 + 0]);
            a1[q * 4 + 1] = fmaf(hj, v1.y, a1[q * 4 + 1]);
            a1[q * 4 + 2] = fmaf(hj, v1.z, a1[q * 4 + 2]);
            a1[q * 4 + 3] = fmaf(hj, v1.w, a1[q * 4 + 3]);
            aR[q * 4 + 0] = fmaf(hj, vr.x, aR[q * 4 + 0]);
            aR[q * 4 + 1] = fmaf(hj, vr.y, aR[q * 4 + 1]);
            aR[q * 4 + 2] = fmaf(hj, vr.z, aR[q * 4 + 2]);
            aR[q * 4 + 3] = fmaf(hj, vr.w, aR[q * 4 + 3]);
        }
    }

    if (valid) {
#pragma unroll
        for (int k = 0; k < 16; ++k)
            stageU[t * 17 + k] = f2bf(a1[2 * k]) | (f2bf(a1[2 * k + 1]) << 16);
    }
    __syncthreads();
#pragma unroll
    for (int it = 0; it < 4; ++it) {
        int idx4 = t + 256 * it;
        if (idx4 < validN * 4) {
            int node = idx4 >> 2, q = (idx4 & 3) * 4;
            uint4 v = make_uint4(stageU[node * 17 + q], stageU[node * 17 + q + 1],
                                 stageU[node * 17 + q + 2], stageU[node * 17 + q + 3]);
            ((uint4*)tb1)[(size_t)blk * 1024 + idx4] = v;
        }
    }

#pragma unroll 1
    for (int p = 0; p < 2; ++p) {
        __syncthreads();
        int l = t - p * 128;
        if (l >= 0 && l < 128 && valid) {
#pragma unroll
            for (int k = 0; k < 32; ++k) stageF[l * 33 + k] = aR[k];
        }
        __syncthreads();
        int remN = NB - blk * 256 - p * 128;
        int validNp = remN < 0 ? 0 : (remN > 128 ? 128 : remN);
#pragma unroll
        for (int it = 0; it < 4; ++it) {
            int idx4 = t + 256 * it;
            if (idx4 < validNp * 8) {
                int node = idx4 >> 3, q = (idx4 & 7) * 4;
                float4 v = make_float4(stageF[node * 33 + q], stageF[node * 33 + q + 1],
                                       stageF[node * 33 + q + 2], stageF[node * 33 + q + 3]);
                ((float4*)outb)[(size_t)blk * 2048 + p * 1024 + idx4] = v;
            }
        }
    }
}

extern "C" void kernel_launch(void* const* d_in, const int* in_sizes, int n_in,
                              void* d_out, int out_size, void* d_ws, size_t ws_size,
                              hipStream_t stream) {
    const float* x_a    = (const float*)d_in[0];
    const float* x_b    = (const float*)d_in[1];
    const int*   ei_ab  = (const int*)d_in[2];
    const int*   ei_ba  = (const int*)d_in[3];
    const int*   ei_aa  = (const int*)d_in[4];
    const float* Wrel1  = (const float*)d_in[5];
    const float* Wroot1 = (const float*)d_in[6];
    const float* b1     = (const float*)d_in[7];
    const float* Wrel2  = (const float*)d_in[8];
    const float* Wroot2 = (const float*)d_in[9];
    const float* b2     = (const float*)d_in[10];

    float* outa = (float*)d_out;                       // [NA,32]
    float* outb = (float*)d_out + (size_t)NA * 32;     // [NB,32]

    char* ws = (char*)d_ws;
    uint32_t* buck_a   = (uint32_t*)(ws);                    // 3907*704*4  = 11,002,112
    uint32_t* buck_b   = (uint32_t*)(ws + 11002112);         // 3907*416*4  =  6,501,248
    float*    agg_ba   = (float*)(ws + 17503360);            // NA floats
    float*    agg_aa   = (float*)(ws + 19503360);            // NA floats
    float*    agg_ab   = (float*)(ws + 21503360);            // NB floats
    uint16_t* ta0      = (uint16_t*)(ws + 23503360);         // NA*32 bf16
    uint16_t* ta2      = (uint16_t*)(ws + 55503360);         // NA*32 bf16
    uint16_t* tb1      = (uint16_t*)(ws + 87503360);         // NB*32 bf16
    uint16_t* start16_a= (uint16_t*)(ws + 119503360);        // 3907*128 u16
    uint16_t* start16_b= (uint16_t*)(ws + 120503552);        // 3907*128 u16
    int*      cnt_a    = (int*)(ws + 121503744);             // 3907 int
    int*      cnt_b    = (int*)(ws + 121519376);             // 3907 int
    int*      ocnt     = (int*)(ws + 121535008);             // 1 int
    uint2*    oflow    = (uint2*)(ws + 121535016);           // 4096 uint2
    if (ws_size < 121600000) return;  // need ~121.6 MB scratch

    // zero cnt_a, cnt_b, ocnt (contiguous span)
    hipMemsetAsync(ws + 121503744 + 2000000 - 2000000, 0, 0, stream); // no-op guard
    hipMemsetAsync(ws + 121503744, 0, 0, stream);                     // no-op
    hipMemsetAsync((char*)cnt_a, 0, 121535016 - 121503744, stream);

    dim3 blk(256);
    int egrid = (3 * EE + 255) / 256;
    bucket_scatter<<<egrid, blk, 0, stream>>>(ei_ab, ei_ba, ei_aa, cnt_a, cnt_b,
                                              buck_a, buck_b, ocnt, oflow);

    sort_agg<<<dim3(NBUCK, 2), blk, 0, stream>>>(cnt_a, cnt_b, buck_a, buck_b,
                                                 x_a, x_b, agg_ba, agg_aa, agg_ab,
                                                 start16_a, start16_b);
    oflow_agg<<<1, blk, 0, stream>>>(ocnt, oflow, x_a, x_b, agg_ba, agg_aa, agg_ab);

    int ngrid = (NA + 255) / 256;
    node_a_kernel<<<ngrid, blk, 0, stream>>>(x_a, agg_ba, agg_aa, Wrel1, Wroot1,
                                             b1, Wrel2, Wroot2, b2, ta0, ta2, outa);
    node_b_kernel<<<ngrid, blk, 0, stream>>>(x_b, agg_ab, Wrel1, Wroot1, b1,
                                             Wrel2, Wroot2, b2, tb1, outb);

    int ggrid = (int)(((size_t)(NA + NB) * 8) / 256);  // 31250 exact
    gather_out<<<ggrid, blk, 0, stream>>>(cnt_a, cnt_b, start16_a, start16_b,
                                          buck_a, buck_b, ta0, ta2, tb1,
                                          outa, outb);
    oflow_out<<<1, blk, 0, stream>>>(ocnt, oflow, ta0, ta2, tb1, outa, outb);
}